// Round 3
// baseline (218.826 us; speedup 1.0000x reference)
//
#include <hip/hip_runtime.h>

// Post_Prob_GS: B=8, N=256 points, grid 128x128 (HW=16384), stride 4.
// out[b, n, hw] = softmax over n of likelihood; n==256 is the background term.
//
// Round 3 structure:
//  - prep kernel packs per-point coeffs (expanded quadratic, log2e-scaled).
//  - main kernel: block = 256 threads = 64 hw cells x 4 n-quadrants.
//    Each thread does a 3-pass softmax over its 64 points; quadrant merge
//    through LDS (ascending-q strict-> merge == jnp.argmax first-max).
//    8192 waves total -> 8 waves/SIMD (vs 2 before) for latency hiding.

#define HWC 16384
#define NPTS 256
#define NBATCH 8

#define K_LOG2E 1.4426950408889634f
// log2e*(-0.5*100^2) + log2(0.15)
#define BK_CONST (-7216.2121700389835f)

__global__ __launch_bounds__(256) void prep_kernel(
    const float* __restrict__ scale,     // (B,N,2)
    const float* __restrict__ rotation,  // (B,N,1)
    const float* __restrict__ points,    // (B,N,2)
    float4* __restrict__ P)              // (B*N) x 2 float4
{
    const int i = blockIdx.x * 256 + threadIdx.x;   // 0..2047 = b*256+n
    if (i >= NBATCH * NPTS) return;

    float sx = fminf(fmaxf(32.0f * scale[i * 2 + 0], 2.0f), 100.0f);
    float sy = fminf(fmaxf(32.0f * scale[i * 2 + 1], 2.0f), 100.0f);
    float sx2 = sx * sx, sy2 = sy * sy;

    float th = rotation[i];
    float s, c;
    sincosf(th, &s, &c);
    float cov_a = c * c * sx2 + s * s * sy2;
    float cov_b = c * s * (sx2 - sy2);
    float cov_d = s * s * sx2 + c * c * sy2;
    float det  = sx2 * sy2;
    float rdet = 1.0f / det;

    // z = -0.5*(inv_a dx^2 + 2 inv_b dx dy + inv_d dy^2); all scaled by log2e
    float KA = -0.5f * K_LOG2E * (cov_d * rdet);
    float KB =         K_LOG2E * (cov_b * rdet);
    float KD = -0.5f * K_LOG2E * (cov_a * rdet);

    float px = points[i * 2 + 0];
    float py = points[i * 2 + 1];

    // expand: zK = KA*gx^2 + KB*gx*gy + KD*gy^2 + cx*gx + cy*gy + cz
    float cx = -(2.0f * KA * px + KB * py);
    float cy = -(KB * px + 2.0f * KD * py);
    float cz = KA * px * px + KB * px * py + KD * py * py;

    float l2det = log2f(det);
    float HLK = -0.5f * l2det;

    P[i * 2 + 0] = make_float4(KA, KB, KD, cx);
    P[i * 2 + 1] = make_float4(cy, cz + HLK, HLK, l2det);
}

#define LIKE(q0, q1) fmaf((q0).x, gxx, fmaf((q0).y, gxy, fmaf((q0).z, gyy, \
                     fmaf((q0).w, gx,  fmaf((q1).x, gy, (q1).y)))))

__global__ __launch_bounds__(256) void post_prob_kernel(
    const float4* __restrict__ P,   // packed coeffs in ws
    float* __restrict__ out)        // (B, 257, HW)
{
    __shared__ float sM[256];
    __shared__ float sBZ[256];
    __shared__ float sBLD[256];
    __shared__ float sS[256];

    const int b      = blockIdx.x >> 8;          // 256 blocks per batch
    const int hwbase = (blockIdx.x & 255) << 6;  // 64 hw per block
    const int tid    = threadIdx.x;
    const int h      = tid & 63;                 // hw within block
    const int nq     = tid >> 6;                 // n-quadrant (= wave id)
    const int hw     = hwbase + h;

    const float gx = (float)((hw & 127) * 4 + 2);
    const float gy = (float)((hw >> 7) * 4 + 2);
    const float gxx = gx * gx, gxy = gx * gy, gyy = gy * gy;

    const float4* __restrict__ Pb = P + ((size_t)b * NPTS + nq * 64) * 2;

    // ---- pass 1: per-thread max of likeK + first-argmax of zK over 64 pts ----
    float m = -INFINITY, bz = -INFINITY, bld = 0.0f;
    #pragma unroll 8
    for (int i = 0; i < 64; ++i) {
        float4 q0 = Pb[i * 2 + 0];
        float4 q1 = Pb[i * 2 + 1];
        float like = LIKE(q0, q1);
        float z = like - q1.z;
        m = fmaxf(m, like);
        bool gt = z > bz;               // strict > : first occurrence wins
        bz  = gt ? z    : bz;
        bld = gt ? q1.w : bld;
    }
    sM[tid] = m; sBZ[tid] = bz; sBLD[tid] = bld;
    __syncthreads();

    // merge quadrants in ascending q (== ascending n: first-max wins)
    float mf = sM[h], bzf = sBZ[h], bldf = sBLD[h];
    #pragma unroll
    for (int q = 1; q < 4; ++q) {
        mf = fmaxf(mf, sM[h + q * 64]);
        float zq = sBZ[h + q * 64];
        bool gt = zq > bzf;
        bzf  = gt ? zq : bzf;
        bldf = gt ? sBLD[h + q * 64] : bldf;
    }
    const float bk = BK_CONST - bzf - bldf;
    mf = fmaxf(mf, bk);

    // ---- pass 2: per-thread sum of exp2, then quadrant-sum merge ----
    float s = 0.0f;
    #pragma unroll 8
    for (int i = 0; i < 64; ++i) {
        float4 q0 = Pb[i * 2 + 0];
        float4 q1 = Pb[i * 2 + 1];
        s += exp2f(LIKE(q0, q1) - mf);
    }
    sS[tid] = s;
    __syncthreads();
    float sum = sS[h] + sS[h + 64] + sS[h + 128] + sS[h + 192] + exp2f(bk - mf);
    const float m2 = mf + log2f(sum);   // fold 1/sum into the exponent

    // ---- pass 3: writes; each wave stores 64 contiguous floats per instr ----
    float* __restrict__ outb = out + ((size_t)b * 257 + nq * 64) * HWC + hw;
    #pragma unroll 8
    for (int i = 0; i < 64; ++i) {
        float4 q0 = Pb[i * 2 + 0];
        float4 q1 = Pb[i * 2 + 1];
        outb[(size_t)i * HWC] = exp2f(LIKE(q0, q1) - m2);
    }
    if (tid < 64)
        out[((size_t)b * 257 + 256) * HWC + hw] = exp2f(bk - m2);
}

extern "C" void kernel_launch(void* const* d_in, const int* in_sizes, int n_in,
                              void* d_out, int out_size, void* d_ws, size_t ws_size,
                              hipStream_t stream) {
    const float* scale    = (const float*)d_in[0];
    const float* rotation = (const float*)d_in[1];
    const float* points   = (const float*)d_in[2];
    float* out = (float*)d_out;
    float4* P  = (float4*)d_ws;
    (void)in_sizes; (void)n_in; (void)out_size; (void)ws_size;

    prep_kernel<<<dim3(NBATCH), dim3(256), 0, stream>>>(scale, rotation, points, P);
    post_prob_kernel<<<dim3(NBATCH * (HWC / 64)), dim3(256), 0, stream>>>(P, out);
}

// Round 4
// 146.259 us; speedup vs baseline: 1.4962x; 1.4962x over previous
//
#include <hip/hip_runtime.h>

// Post_Prob_GS: B=8, N=256 points, grid 128x128 (HW=16384), stride 4.
// out[b, n, hw] = softmax over n of likelihood; n==256 is the background term.
//
// Round 4 structure:
//  - prep kernel packs per-point coeffs (expanded quadratic, log2e-scaled).
//  - main kernel: block = 512 threads = 64 hw cells x 8 n-groups of 32 points.
//    Each thread computes its 32 likes ONCE into a register cache (fully
//    unrolled, compile-time indices), merges max/argmax + sum across groups
//    via LDS, then writes e*inv. Coefficient base made wave-uniform via
//    readfirstlane -> s_load (constant cache) instead of per-lane VMEM.

#define HWC 16384
#define NPTS 256
#define NBATCH 8

#define K_LOG2E 1.4426950408889634f
// log2e*(-0.5*100^2) + log2(0.15)
#define BK_CONST (-7216.2121700389835f)

__global__ __launch_bounds__(256) void prep_kernel(
    const float* __restrict__ scale,     // (B,N,2)
    const float* __restrict__ rotation,  // (B,N,1)
    const float* __restrict__ points,    // (B,N,2)
    float4* __restrict__ P)              // (B*N) x 2 float4
{
    const int i = blockIdx.x * 256 + threadIdx.x;   // 0..2047 = b*256+n
    if (i >= NBATCH * NPTS) return;

    float sx = fminf(fmaxf(32.0f * scale[i * 2 + 0], 2.0f), 100.0f);
    float sy = fminf(fmaxf(32.0f * scale[i * 2 + 1], 2.0f), 100.0f);
    float sx2 = sx * sx, sy2 = sy * sy;

    float th = rotation[i];
    float s, c;
    sincosf(th, &s, &c);
    float cov_a = c * c * sx2 + s * s * sy2;
    float cov_b = c * s * (sx2 - sy2);
    float cov_d = s * s * sx2 + c * c * sy2;
    float det  = sx2 * sy2;
    float rdet = 1.0f / det;

    // z = -0.5*(inv_a dx^2 + 2 inv_b dx dy + inv_d dy^2); all scaled by log2e
    float KA = -0.5f * K_LOG2E * (cov_d * rdet);
    float KB =         K_LOG2E * (cov_b * rdet);
    float KD = -0.5f * K_LOG2E * (cov_a * rdet);

    float px = points[i * 2 + 0];
    float py = points[i * 2 + 1];

    // expand: zK = KA*gx^2 + KB*gx*gy + KD*gy^2 + cx*gx + cy*gy + cz
    float cx = -(2.0f * KA * px + KB * py);
    float cy = -(KB * px + 2.0f * KD * py);
    float cz = KA * px * px + KB * px * py + KD * py * py;

    float l2det = log2f(det);
    float HLK = -0.5f * l2det;

    P[i * 2 + 0] = make_float4(KA, KB, KD, cx);
    P[i * 2 + 1] = make_float4(cy, cz + HLK, HLK, l2det);
}

#define LIKE(q0, q1) fmaf((q0).x, gxx, fmaf((q0).y, gxy, fmaf((q0).z, gyy, \
                     fmaf((q0).w, gx,  fmaf((q1).x, gy, (q1).y)))))

__global__ __launch_bounds__(512) void post_prob_kernel(
    const float4* __restrict__ P,   // packed coeffs in ws
    float* __restrict__ out)        // (B, 257, HW)
{
    __shared__ float sM[512];
    __shared__ float sBZ[512];
    __shared__ float sBLD[512];
    __shared__ float sS[512];

    const int b      = blockIdx.x >> 8;          // 256 blocks per batch
    const int hwbase = (blockIdx.x & 255) << 6;  // 64 hw per block
    const int tid    = threadIdx.x;
    const int h      = tid & 63;                 // hw within block (lane)
    const int hw     = hwbase + h;
    // n-group 0..7; readfirstlane => SGPR => scalar coefficient loads
    const int g      = __builtin_amdgcn_readfirstlane(tid >> 6);

    const float gx = (float)((hw & 127) * 4 + 2);
    const float gy = (float)((hw >> 7) * 4 + 2);
    const float gxx = gx * gx, gxy = gx * gy, gyy = gy * gy;

    const float4* __restrict__ Pb = P + (b * NPTS + g * 32) * 2;

    // ---- pass A: compute 32 likes into register cache; track max + argmax ----
    float lk[32];
    float m = -INFINITY, bz = -INFINITY, bld = 0.0f;
    #pragma unroll
    for (int i = 0; i < 32; ++i) {
        float4 q0 = Pb[i * 2 + 0];
        float4 q1 = Pb[i * 2 + 1];
        float like = LIKE(q0, q1);
        lk[i] = like;
        m = fmaxf(m, like);
        float z = like - q1.z;
        bool gt = z > bz;               // strict > : first occurrence wins
        bz  = gt ? z    : bz;
        bld = gt ? q1.w : bld;
    }
    sM[tid] = m; sBZ[tid] = bz; sBLD[tid] = bld;
    __syncthreads();

    // merge groups in ascending g (== ascending n: first-max wins)
    float mf = sM[h], bzf = sBZ[h], bldf = sBLD[h];
    #pragma unroll
    for (int q = 1; q < 8; ++q) {
        mf = fmaxf(mf, sM[h + q * 64]);
        float zq = sBZ[h + q * 64];
        bool gt = zq > bzf;
        bzf  = gt ? zq : bzf;
        bldf = gt ? sBLD[h + q * 64] : bldf;
    }
    const float bk = BK_CONST - bzf - bldf;
    mf = fmaxf(mf, bk);

    // ---- pass B: exponentiate cache in place, accumulate partial sum ----
    float s = 0.0f;
    #pragma unroll
    for (int i = 0; i < 32; ++i) {
        float e = exp2f(lk[i] - mf);
        lk[i] = e;
        s += e;
    }
    sS[tid] = s;
    __syncthreads();

    float sum = exp2f(bk - mf);
    #pragma unroll
    for (int q = 0; q < 8; ++q) sum += sS[h + q * 64];
    const float inv = 1.0f / sum;

    // ---- pass C: normalized writes; each wave stores 64x4B contiguous ----
    float* __restrict__ outb = out + ((size_t)b * 257 + g * 32) * HWC + hw;
    #pragma unroll
    for (int i = 0; i < 32; ++i)
        outb[(size_t)i * HWC] = lk[i] * inv;

    if (tid < 64)
        out[((size_t)b * 257 + 256) * HWC + hw] = exp2f(bk - mf) * inv;
}

extern "C" void kernel_launch(void* const* d_in, const int* in_sizes, int n_in,
                              void* d_out, int out_size, void* d_ws, size_t ws_size,
                              hipStream_t stream) {
    const float* scale    = (const float*)d_in[0];
    const float* rotation = (const float*)d_in[1];
    const float* points   = (const float*)d_in[2];
    float* out = (float*)d_out;
    float4* P  = (float4*)d_ws;
    (void)in_sizes; (void)n_in; (void)out_size; (void)ws_size;

    prep_kernel<<<dim3(NBATCH), dim3(256), 0, stream>>>(scale, rotation, points, P);
    post_prob_kernel<<<dim3(NBATCH * (HWC / 64)), dim3(512), 0, stream>>>(P, out);
}